// Round 3
// baseline (437.813 us; speedup 1.0000x reference)
//
#include <hip/hip_runtime.h>

#define BATCH 16
#define CIN   64
#define HW    128
#define OC    128
#define KSIZE 576   // 64 * 9

typedef float float4v __attribute__((ext_vector_type(4)));
typedef int   int4v   __attribute__((ext_vector_type(4)));
typedef unsigned int uint;

// workspace layout (float offsets)
#define WS_ACT   0      // act_scale[576], k = c*9 + r order
#define WS_WSC   576    // weight_scale[576]
#define WS_XMUL  1152   // xmul[r*64+c] = 1/(scale[c*9+r]*s_x)
#define WS_SXSW  1728
#define WS_WQ_BYTE_OFF 8192   // int8 wq_s[9][128][64], frags XOR-pre-swizzled

#define SWZ(x) ((((x) & 3) ^ (((x) >> 2) & 3)))
#define MAGIC 12582912.0f   // 1.5 * 2^23: fma bias => round-half-even int8 in low byte

__device__ __forceinline__ void async_cp16(const void* g, void* l) {
    __builtin_amdgcn_global_load_lds(
        (const __attribute__((address_space(1))) unsigned int*)g,
        (__attribute__((address_space(3))) unsigned int*)l, 16, 0, 0);
}

// ---------------------------------------------------------------------------
// Kernel 1: fused absmax (unchanged — validated R2-R4).
// ---------------------------------------------------------------------------
__global__ __launch_bounds__(256) void k_absmax(const float* __restrict__ in,
                                                const float* __restrict__ w,
                                                float* __restrict__ wsf) {
    const int tid = threadIdx.x, lane = tid & 63, wid = tid >> 6;
    if (blockIdx.x < 1024) {
        const int c = blockIdx.x >> 4, bs = blockIdx.x & 15;
        const float4v* p = (const float4v*)(in + (size_t)(bs * CIN + c) * (HW * HW));
        float m[9];
#pragma unroll
        for (int i = 0; i < 9; ++i) m[i] = 0.f;
        for (int e = tid; e < 4096; e += 256) {
            const int h = e >> 5, q = e & 31;
            const float4v v = p[e];
            const float a0 = fabsf(v[0]), a1 = fabsf(v[1]), a2 = fabsf(v[2]), a3 = fabsf(v[3]);
            const float m01 = fmaxf(a0, a1), m12 = fmaxf(a1, a2);
            const float mall = fmaxf(m01, fmaxf(a2, a3));
            const float mw0 = (q == 31) ? fmaxf(m01, a2) : mall;
            const float mw2 = (q == 0)  ? fmaxf(m12, a3) : mall;
            const bool h0 = (h <= 126), h2 = (h >= 1);
            m[0] = fmaxf(m[0], h0 ? mw0 : 0.f);
            m[1] = fmaxf(m[1], h0 ? mall : 0.f);
            m[2] = fmaxf(m[2], h0 ? mw2 : 0.f);
            m[3] = fmaxf(m[3], mw0);
            m[4] = fmaxf(m[4], mall);
            m[5] = fmaxf(m[5], mw2);
            m[6] = fmaxf(m[6], h2 ? mw0 : 0.f);
            m[7] = fmaxf(m[7], h2 ? mall : 0.f);
            m[8] = fmaxf(m[8], h2 ? mw2 : 0.f);
        }
#pragma unroll
        for (int i = 0; i < 9; ++i)
            for (int off = 32; off; off >>= 1)
                m[i] = fmaxf(m[i], __shfl_down(m[i], off));
        __shared__ float sred[4][9];
        if (lane == 0)
#pragma unroll
            for (int i = 0; i < 9; ++i) sred[wid][i] = m[i];
        __syncthreads();
        if (tid < 9) {
            float mm = fmaxf(fmaxf(sred[0][tid], sred[1][tid]),
                             fmaxf(sred[2][tid], sred[3][tid]));
            atomicMax((int*)(wsf + WS_ACT + c * 9 + tid), __float_as_int(mm));
        }
    } else {
        const int k = (blockIdx.x - 1024) * 4 + wid;
        float m = fmaxf(fabsf(w[lane * KSIZE + k]), fabsf(w[(lane + 64) * KSIZE + k]));
        for (int off = 32; off; off >>= 1) m = fmaxf(m, __shfl_down(m, off));
        if (lane == 0) wsf[WS_WSC + k] = m;
    }
}

// ---------------------------------------------------------------------------
// Kernel 2: scale + weight quantize -> int8, pre-swizzled (unchanged — validated R3/R4).
// ---------------------------------------------------------------------------
__global__ __launch_bounds__(576) void k_scale_wq(const float* __restrict__ w,
                                                  float* __restrict__ wsf,
                                                  char* __restrict__ wq_s) {
    __shared__ float ls[576];
    __shared__ float redA[9], redB[9];
    const int t = threadIdx.x, o = blockIdx.x;
    const int lane = t & 63, wid = t >> 6;
    const float a = wsf[WS_ACT + t];
    const float wv = wsf[WS_WSC + t];
    float s = sqrtf(a) / sqrtf(wv);
    if (s == 0.f) s = 1.f;
    ls[t] = s;
    float v1 = a / s;
    float v2 = wv * s;
    for (int off = 32; off; off >>= 1) {
        v1 = fmaxf(v1, __shfl_down(v1, off));
        v2 = fmaxf(v2, __shfl_down(v2, off));
    }
    if (lane == 0) { redA[wid] = v1; redB[wid] = v2; }
    __syncthreads();
    float ax = redA[0], aw = redB[0];
#pragma unroll
    for (int i = 1; i < 9; ++i) { ax = fmaxf(ax, redA[i]); aw = fmaxf(aw, redB[i]); }
    const float sx = ax > 0.f ? ax / 127.f : 1.f;
    const float sw = aw > 0.f ? aw / 127.f : 1.f;
    const int r = t >> 6, c = t & 63, ko = c * 9 + r;
    float q = rintf((w[o * KSIZE + ko] * ls[ko]) / sw);
    q = fminf(127.f, fmaxf(-127.f, q));
    const int qi = (int)q;
    const int fc = c >> 4;
    wq_s[r * 8192 + o * 64 + ((fc ^ SWZ(o)) << 4) + (c & 15)] = (char)qi;
    if (o == 0) {
        wsf[WS_XMUL + t] = 1.0f / (ls[ko] * sx);   // [r][c] layout
        if (t == 0) wsf[WS_SXSW] = sx * sw;
    }
}

// ---------------------------------------------------------------------------
// helpers for v5's branch-free addressing (R,F compile-time constants)
// ---------------------------------------------------------------------------
__device__ __forceinline__ const float* a_ptr(const float* pb, int oh, int ow0,
                                              int R, int F) {
    const int kh = R / 3, kw = R % 3;
    int h = oh + kh - 1;
    h = h < 0 ? 0 : (h > 127 ? 127 : h);
    int iw = ow0 + (F ? 16 : 0) + kw - 1;
    if (kw == 0 && F == 0) iw = iw < 0 ? 0 : iw;     // only frag0 can underflow
    if (kw == 2 && F == 1) iw = iw > 127 ? 127 : iw; // only frag1 can overflow
    return pb + h * HW + iw;
}

__device__ __forceinline__ uint a_msk(int oh, int ow0, int R, int F) {
    const int kh = R / 3, kw = R % 3;
    const int h = oh + kh - 1;
    uint m = ((unsigned)h < 128u) ? 0xFFFFFFFFu : 0u;
    const int iw = ow0 + (F ? 16 : 0) + kw - 1;
    if ((kw == 0 && F == 0) || (kw == 2 && F == 1))
        if (!((unsigned)iw < 128u)) m = 0u;
    return m;
}

// ---------------------------------------------------------------------------
// Kernel 3: i8 implicit-GEMM conv, v5: half-chunk software pipeline.
// Block = (b, oh-pair), 512 thr = 8 waves, wave tile 32ow x 128oc (v3 core).
// 18 half-chunks (r, frag); each: quantize vb[f] -> issue loads for
// half-chunk+2 (prefetch distance = 1 full chunk) -> 8 MFMA. Branch-free
// clamp+mask (v4-validated numerics). Register-safe: persistent vb[2][16]=32
// VGPR + transients ~= 60 VGPR beside 64 AGPR acc -> fits the 64/64 split of
// the (512,4) 128-reg budget (v4's spill lesson). bf not shared across frags
// (2x ds_read_b128 vs v3) -- LDS slack proven in R1.
// ---------------------------------------------------------------------------
__global__ __launch_bounds__(512, 4) void k_gemm(const float* __restrict__ in,
                                                 const char* __restrict__ wq_s,
                                                 const float* __restrict__ wsf,
                                                 float* __restrict__ out) {
    __shared__ int4v Bl4[4608];        // 73728 B: 9 planes of [o=128][c=64] i8
    __shared__ float xml[576];
    char* Bl = (char*)Bl4;

    const int tid = threadIdx.x, lane = tid & 63, w = tid >> 6;
    // XCD swizzle: each XCD owns a 16-row oh band per batch (L2 input reuse).
    const int xcd = blockIdx.x & 7, idx = blockIdx.x >> 3;
    const int ohp = idx & 7;               // oh-pair index inside band
    const int b = idx >> 3;                // batch
    const int wh = w >> 2, wm = w & 3;     // oh-half, ow-quarter
    const int oh = xcd * 16 + ohp * 2 + wh;
    const int l15 = lane & 15, fsel = lane >> 4;
    const int ow0 = wm * 32 + l15;         // frag0 M index; frag1 = ow0 + 16

    // ---- prologue: B staging + xml + prefetch half-chunks 0,1 ----
#pragma unroll
    for (int i = 0; i < 9; ++i)
        async_cp16(wq_s + i * 8192 + tid * 16, Bl + i * 8192 + tid * 16);
    if (tid < 144)
        ((float4v*)xml)[tid] = ((const float4v*)(wsf + WS_XMUL))[tid];

    const float* pb = in + ((size_t)b * CIN + fsel * 16) * (HW * HW);

    float vbuf[2][16];
    {
        const float* p0 = a_ptr(pb, oh, ow0, 0, 0);
        const float* p1 = a_ptr(pb, oh, ow0, 0, 1);
#pragma unroll
        for (int j = 0; j < 16; ++j) {
            vbuf[0][j] = p0[j * (HW * HW)];
            vbuf[1][j] = p1[j * (HW * HW)];
        }
    }

    int4v acc0[8], acc1[8];
#pragma unroll
    for (int nt = 0; nt < 8; ++nt) {
        acc0[nt] = (int4v){0, 0, 0, 0};
        acc1[nt] = (int4v){0, 0, 0, 0};
    }

    __syncthreads();   // B + xml ready (implicit vmcnt(0) also covers prefetch)

#define HALFCHUNK(HC)                                                          \
    {                                                                          \
        constexpr int R = (HC) >> 1, F = (HC) & 1;                             \
        const float* xp = xml + R * 64 + (fsel << 4);                          \
        uint pk[4];                                                            \
        _Pragma("unroll")                                                      \
        for (int d = 0; d < 4; ++d) {                                          \
            const float4v xq = *(const float4v*)(xp + d * 4);                  \
            uint u[4];                                                         \
            _Pragma("unroll")                                                  \
            for (int j2 = 0; j2 < 4; ++j2)                                     \
                u[j2] = __float_as_uint(fmaf(vbuf[F][d * 4 + j2], xq[j2], MAGIC)); \
            const uint p01 = __builtin_amdgcn_perm(u[1], u[0], 0x0C0C0400u);   \
            const uint p23 = __builtin_amdgcn_perm(u[3], u[2], 0x0C0C0400u);   \
            pk[d] = __builtin_amdgcn_perm(p23, p01, 0x05040100u);              \
        }                                                                      \
        const uint msk = a_msk(oh, ow0, R, F);                                 \
        const int4v af = (int4v){(int)(pk[0] & msk), (int)(pk[1] & msk),       \
                                 (int)(pk[2] & msk), (int)(pk[3] & msk)};      \
        if ((HC) + 2 < 18) {                                                   \
            const float* pn = a_ptr(pb, oh, ow0, ((HC) + 2) >> 1, F);          \
            _Pragma("unroll")                                                  \
            for (int j = 0; j < 16; ++j) vbuf[F][j] = pn[j * (HW * HW)];       \
        }                                                                      \
        if (F == 0) {                                                          \
            _Pragma("unroll")                                                  \
            for (int nt = 0; nt < 8; ++nt) {                                   \
                const int br = nt * 16 + l15;                                  \
                const int4v bf = *(const int4v*)(Bl + R * 8192 + br * 64 +     \
                                                 ((fsel ^ SWZ(br)) << 4));     \
                acc0[nt] = __builtin_amdgcn_mfma_i32_16x16x64_i8(af, bf,       \
                                                          acc0[nt], 0, 0, 0); \
            }                                                                  \
        } else {                                                               \
            _Pragma("unroll")                                                  \
            for (int nt = 0; nt < 8; ++nt) {                                   \
                const int br = nt * 16 + l15;                                  \
                const int4v bf = *(const int4v*)(Bl + R * 8192 + br * 64 +     \
                                                 ((fsel ^ SWZ(br)) << 4));     \
                acc1[nt] = __builtin_amdgcn_mfma_i32_16x16x64_i8(af, bf,       \
                                                          acc1[nt], 0, 0, 0); \
            }                                                                  \
        }                                                                      \
    }

    HALFCHUNK(0)  HALFCHUNK(1)  HALFCHUNK(2)  HALFCHUNK(3)  HALFCHUNK(4)
    HALFCHUNK(5)  HALFCHUNK(6)  HALFCHUNK(7)  HALFCHUNK(8)  HALFCHUNK(9)
    HALFCHUNK(10) HALFCHUNK(11) HALFCHUNK(12) HALFCHUNK(13) HALFCHUNK(14)
    HALFCHUNK(15) HALFCHUNK(16) HALFCHUNK(17)
#undef HALFCHUNK

    // ---- epilogue: row=(lane>>4)*4+reg -> ow, col=lane&15 -> o ----
    const float sxsw = wsf[WS_SXSW];
    const int owp = wm * 32 + (fsel << 2);
#pragma unroll
    for (int nt = 0; nt < 8; ++nt) {
        const int o = nt * 16 + l15;
        float4v rv0, rv1;
#pragma unroll
        for (int q = 0; q < 4; ++q) {
            rv0[q] = (float)acc0[nt][q] * sxsw;
            rv1[q] = (float)acc1[nt][q] * sxsw;
        }
        float* po = out + ((size_t)(b * OC + o) * HW + oh) * HW;
        *(float4v*)(po + owp) = rv0;
        *(float4v*)(po + owp + 16) = rv1;
    }
}

// ---------------------------------------------------------------------------
extern "C" void kernel_launch(void* const* d_in, const int* in_sizes, int n_in,
                              void* d_out, int out_size, void* d_ws, size_t ws_size,
                              hipStream_t stream) {
    const float* in = (const float*)d_in[0];   // (16, 64, 128, 128) fp32
    const float* wt = (const float*)d_in[1];   // (128, 64, 3, 3) fp32
    float* out = (float*)d_out;                // (16, 128, 128, 128) fp32
    float* wsf = (float*)d_ws;
    char* wq_s = (char*)d_ws + WS_WQ_BYTE_OFF;

    k_absmax<<<dim3(1024 + 144), dim3(256), 0, stream>>>(in, wt, wsf);
    k_scale_wq<<<dim3(128), dim3(576), 0, stream>>>(wt, wsf, wq_s);
    k_gemm<<<dim3(BATCH * HW / 2), dim3(512), 0, stream>>>(in, wq_s, wsf, out);
}

// Round 5
// 278.112 us; speedup vs baseline: 1.5742x; 1.5742x over previous
//
#include <hip/hip_runtime.h>

#define BATCH 16
#define CIN   64
#define HW    128
#define OC    128
#define KSIZE 576   // 64 * 9

typedef float float4v __attribute__((ext_vector_type(4)));
typedef int   int4v   __attribute__((ext_vector_type(4)));
typedef unsigned int uint;

// workspace layout (float offsets)
#define WS_ACT   0      // act_scale[576], k = c*9 + r order
#define WS_WSC   576    // weight_scale[576]
#define WS_XMUL  1152   // xmul[r*64+c] = 1/(scale[c*9+r]*s_x)
#define WS_SXSW  1728
#define WS_WQ_BYTE_OFF 8192   // int8 wq_s[9][128][64], frags XOR-pre-swizzled

#define SWZ(x) ((((x) & 3) ^ (((x) >> 2) & 3)))
#define MAGIC 12582912.0f   // 1.5 * 2^23: fma bias => round-half-even int8 in low byte

__device__ __forceinline__ void async_cp16(const void* g, void* l) {
    __builtin_amdgcn_global_load_lds(
        (const __attribute__((address_space(1))) unsigned int*)g,
        (__attribute__((address_space(3))) unsigned int*)l, 16, 0, 0);
}

// ---------------------------------------------------------------------------
// Kernel 1: fused absmax (unchanged — validated R2-R4).
// ---------------------------------------------------------------------------
__global__ __launch_bounds__(256) void k_absmax(const float* __restrict__ in,
                                                const float* __restrict__ w,
                                                float* __restrict__ wsf) {
    const int tid = threadIdx.x, lane = tid & 63, wid = tid >> 6;
    if (blockIdx.x < 1024) {
        const int c = blockIdx.x >> 4, bs = blockIdx.x & 15;
        const float4v* p = (const float4v*)(in + (size_t)(bs * CIN + c) * (HW * HW));
        float m[9];
#pragma unroll
        for (int i = 0; i < 9; ++i) m[i] = 0.f;
        for (int e = tid; e < 4096; e += 256) {
            const int h = e >> 5, q = e & 31;
            const float4v v = p[e];
            const float a0 = fabsf(v[0]), a1 = fabsf(v[1]), a2 = fabsf(v[2]), a3 = fabsf(v[3]);
            const float m01 = fmaxf(a0, a1), m12 = fmaxf(a1, a2);
            const float mall = fmaxf(m01, fmaxf(a2, a3));
            const float mw0 = (q == 31) ? fmaxf(m01, a2) : mall;
            const float mw2 = (q == 0)  ? fmaxf(m12, a3) : mall;
            const bool h0 = (h <= 126), h2 = (h >= 1);
            m[0] = fmaxf(m[0], h0 ? mw0 : 0.f);
            m[1] = fmaxf(m[1], h0 ? mall : 0.f);
            m[2] = fmaxf(m[2], h0 ? mw2 : 0.f);
            m[3] = fmaxf(m[3], mw0);
            m[4] = fmaxf(m[4], mall);
            m[5] = fmaxf(m[5], mw2);
            m[6] = fmaxf(m[6], h2 ? mw0 : 0.f);
            m[7] = fmaxf(m[7], h2 ? mall : 0.f);
            m[8] = fmaxf(m[8], h2 ? mw2 : 0.f);
        }
#pragma unroll
        for (int i = 0; i < 9; ++i)
            for (int off = 32; off; off >>= 1)
                m[i] = fmaxf(m[i], __shfl_down(m[i], off));
        __shared__ float sred[4][9];
        if (lane == 0)
#pragma unroll
            for (int i = 0; i < 9; ++i) sred[wid][i] = m[i];
        __syncthreads();
        if (tid < 9) {
            float mm = fmaxf(fmaxf(sred[0][tid], sred[1][tid]),
                             fmaxf(sred[2][tid], sred[3][tid]));
            atomicMax((int*)(wsf + WS_ACT + c * 9 + tid), __float_as_int(mm));
        }
    } else {
        const int k = (blockIdx.x - 1024) * 4 + wid;
        float m = fmaxf(fabsf(w[lane * KSIZE + k]), fabsf(w[(lane + 64) * KSIZE + k]));
        for (int off = 32; off; off >>= 1) m = fmaxf(m, __shfl_down(m, off));
        if (lane == 0) wsf[WS_WSC + k] = m;
    }
}

// ---------------------------------------------------------------------------
// Kernel 2: scale + weight quantize -> int8, pre-swizzled (unchanged — validated R3/R4).
// ---------------------------------------------------------------------------
__global__ __launch_bounds__(576) void k_scale_wq(const float* __restrict__ w,
                                                  float* __restrict__ wsf,
                                                  char* __restrict__ wq_s) {
    __shared__ float ls[576];
    __shared__ float redA[9], redB[9];
    const int t = threadIdx.x, o = blockIdx.x;
    const int lane = t & 63, wid = t >> 6;
    const float a = wsf[WS_ACT + t];
    const float wv = wsf[WS_WSC + t];
    float s = sqrtf(a) / sqrtf(wv);
    if (s == 0.f) s = 1.f;
    ls[t] = s;
    float v1 = a / s;
    float v2 = wv * s;
    for (int off = 32; off; off >>= 1) {
        v1 = fmaxf(v1, __shfl_down(v1, off));
        v2 = fmaxf(v2, __shfl_down(v2, off));
    }
    if (lane == 0) { redA[wid] = v1; redB[wid] = v2; }
    __syncthreads();
    float ax = redA[0], aw = redB[0];
#pragma unroll
    for (int i = 1; i < 9; ++i) { ax = fmaxf(ax, redA[i]); aw = fmaxf(aw, redB[i]); }
    const float sx = ax > 0.f ? ax / 127.f : 1.f;
    const float sw = aw > 0.f ? aw / 127.f : 1.f;
    const int r = t >> 6, c = t & 63, ko = c * 9 + r;
    float q = rintf((w[o * KSIZE + ko] * ls[ko]) / sw);
    q = fminf(127.f, fmaxf(-127.f, q));
    const int qi = (int)q;
    const int fc = c >> 4;
    wq_s[r * 8192 + o * 64 + ((fc ^ SWZ(o)) << 4) + (c & 15)] = (char)qi;
    if (o == 0) {
        wsf[WS_XMUL + t] = 1.0f / (ls[ko] * sx);   // [r][c] layout
        if (t == 0) wsf[WS_SXSW] = sx * sw;
    }
}

// ---------------------------------------------------------------------------
// Kernel 3: i8 implicit-GEMM conv, v6b: aligned row loads + cross-lane shifts.
// v6 with the shuffle-segment bug fixed: edge-column injection now uses the
// segment-indexed broadcast __shfl(e, j, 16) (v6's __shfl_down(e, j, 16) from
// segment lane 15 addressed lane 15+j — OUTSIDE the width-16 segment ->
// garbage in frag1/kw2 lane 15 for every wave; absmax 5.32).
// Per kh-row: 32 aligned coalesced dwords (R0/R1) + 2 single-column edge
// loads; kw=0/2 fragments derived via segmented shuffles (VALU pipe, idle)
// with boundary injection. VMEM: 288 (2/3 line-crossing) -> 102 aligned
// instr/wave. Numerically exact vs v3.
// ---------------------------------------------------------------------------
__global__ __launch_bounds__(512, 4) void k_gemm(const float* __restrict__ in,
                                                 const char* __restrict__ wq_s,
                                                 const float* __restrict__ wsf,
                                                 float* __restrict__ out) {
    __shared__ int4v Bl4[4608];        // 73728 B: 9 planes of [o=128][c=64] i8
    __shared__ float xml[576];
    char* Bl = (char*)Bl4;

    const int tid = threadIdx.x, lane = tid & 63, w = tid >> 6;
    // XCD swizzle: each XCD owns a 16-row oh band per batch (L2 input reuse).
    const int xcd = blockIdx.x & 7, idx = blockIdx.x >> 3;
    const int ohp = idx & 7;               // oh-pair index inside band
    const int b = idx >> 3;                // batch
    const int wh = w >> 2, wm = w & 3;     // oh-half, ow-quarter
    const int oh = xcd * 16 + ohp * 2 + wh;
    const int l15 = lane & 15, fsel = lane >> 4;
    const int W = wm * 32;                 // wave tile ow base

    // ---- prologue staging (only barrier in the kernel) ----
#pragma unroll
    for (int i = 0; i < 9; ++i)
        async_cp16(wq_s + i * 8192 + tid * 16, Bl + i * 8192 + tid * 16);
    if (tid < 144)
        ((float4v*)xml)[tid] = ((const float4v*)(wsf + WS_XMUL))[tid];
    __syncthreads();

    const float* pb = in + ((size_t)b * CIN + fsel * 16) * (HW * HW);  // row loads
    const float* pe = in + (size_t)b * CIN * (HW * HW);                // edge loads (ch = lane)

    const int colL = (W - 1) < 0 ? 0 : (W - 1);      // clamped; masked if wm==0
    const int colR = (W + 32) > 127 ? 127 : (W + 32);
    const bool isL0  = (l15 == 0);
    const bool isL15 = (l15 == 15);
    const uint mL = (wm == 0 && isL0)  ? 0u : 0xFFFFFFFFu;  // kw0/frag0 OOB lane
    const uint mR = (wm == 3 && isL15) ? 0u : 0xFFFFFFFFu;  // kw2/frag1 OOB lane

    int4v acc0[8], acc1[8];
#pragma unroll
    for (int nt = 0; nt < 8; ++nt) {
        acc0[nt] = (int4v){0, 0, 0, 0};
        acc1[nt] = (int4v){0, 0, 0, 0};
    }

#pragma unroll
    for (int kh = 0; kh < 3; ++kh) {
        const int h = oh + kh - 1;
        if (h >= 0 && h < HW) {            // wave-uniform skip
            // ---- edge columns first (scattered, longest latency; L1-hot) ----
            const float eL = pe[(size_t)lane * (HW * HW) + h * HW + colL];
            const float eR = pe[(size_t)lane * (HW * HW) + h * HW + colR];
            // ---- aligned row loads: 32 coalesced dwords ----
            const float* p = pb + h * HW + W + l15;
            float R0[16], R1[16];
#pragma unroll
            for (int j = 0; j < 16; ++j) {
                R0[j] = p[j * (HW * HW)];
                R1[j] = p[j * (HW * HW) + 16];
            }
            // ---- per-kw: build fragments via shifts, quantize, MFMA ----
#pragma unroll
            for (int kw = 0; kw < 3; ++kw) {
                const int r = kh * 3 + kw;
                const float* xp = xml + r * 64 + (fsel << 4);
                uint pk0[4], pk1[4];
#pragma unroll
                for (int d = 0; d < 4; ++d) {
                    const float4v xq = *(const float4v*)(xp + d * 4);
                    uint u0[4], u1[4];
#pragma unroll
                    for (int j2 = 0; j2 < 4; ++j2) {
                        const int j = d * 4 + j2;
                        float a0, a1;
                        if (kw == 1) {
                            a0 = R0[j];
                            a1 = R1[j];
                        } else if (kw == 0) {
                            const float t0 = __shfl_up(R0[j], 1, 16);
                            const float ev = __shfl(eL, j, 16);      // seg-bcast: lane j of segment holds ch fsel*16+j
                            a0 = isL0 ? ev : t0;
                            const float t1 = __shfl_up(R1[j], 1, 16);
                            const float bb = __shfl(R0[j], 15, 16);  // seg lane 15 bcast
                            a1 = isL0 ? bb : t1;
                        } else {   // kw == 2
                            const float t0 = __shfl_down(R0[j], 1, 16);
                            const float bb = __shfl(R1[j], 0, 16);   // seg lane 0 bcast
                            a0 = isL15 ? bb : t0;
                            const float t1 = __shfl_down(R1[j], 1, 16);
                            const float ev = __shfl(eR, j, 16);      // FIX: seg-bcast (was shfl_down -> OOB from lane 15)
                            a1 = isL15 ? ev : t1;
                        }
                        u0[j2] = __float_as_uint(fmaf(a0, xq[j2], MAGIC));
                        u1[j2] = __float_as_uint(fmaf(a1, xq[j2], MAGIC));
                    }
                    const uint a01 = __builtin_amdgcn_perm(u0[1], u0[0], 0x0C0C0400u);
                    const uint a23 = __builtin_amdgcn_perm(u0[3], u0[2], 0x0C0C0400u);
                    pk0[d] = __builtin_amdgcn_perm(a23, a01, 0x05040100u);
                    const uint b01 = __builtin_amdgcn_perm(u1[1], u1[0], 0x0C0C0400u);
                    const uint b23 = __builtin_amdgcn_perm(u1[3], u1[2], 0x0C0C0400u);
                    pk1[d] = __builtin_amdgcn_perm(b23, b01, 0x05040100u);
                }
                int4v af0, af1;
                if (kw == 0) {             // frag0 lane0 may be image-left OOB
                    af0 = (int4v){(int)(pk0[0] & mL), (int)(pk0[1] & mL),
                                  (int)(pk0[2] & mL), (int)(pk0[3] & mL)};
                    af1 = (int4v){(int)pk1[0], (int)pk1[1], (int)pk1[2], (int)pk1[3]};
                } else if (kw == 2) {      // frag1 lane15 may be image-right OOB
                    af0 = (int4v){(int)pk0[0], (int)pk0[1], (int)pk0[2], (int)pk0[3]};
                    af1 = (int4v){(int)(pk1[0] & mR), (int)(pk1[1] & mR),
                                  (int)(pk1[2] & mR), (int)(pk1[3] & mR)};
                } else {
                    af0 = (int4v){(int)pk0[0], (int)pk0[1], (int)pk0[2], (int)pk0[3]};
                    af1 = (int4v){(int)pk1[0], (int)pk1[1], (int)pk1[2], (int)pk1[3]};
                }
                // ---- B frags (conflict-free swizzle), each feeds 2 MFMA ----
#pragma unroll
                for (int nt = 0; nt < 8; ++nt) {
                    const int br = nt * 16 + l15;
                    const int4v bf = *(const int4v*)(Bl + r * 8192 + br * 64 +
                                                     ((fsel ^ SWZ(br)) << 4));
                    acc0[nt] = __builtin_amdgcn_mfma_i32_16x16x64_i8(af0, bf, acc0[nt], 0, 0, 0);
                    acc1[nt] = __builtin_amdgcn_mfma_i32_16x16x64_i8(af1, bf, acc1[nt], 0, 0, 0);
                }
            }
        }
    }

    // ---- epilogue: row=(lane>>4)*4+reg -> ow, col=lane&15 -> o ----
    const float sxsw = wsf[WS_SXSW];
    const int owp = W + (fsel << 2);
#pragma unroll
    for (int nt = 0; nt < 8; ++nt) {
        const int o = nt * 16 + l15;
        float4v rv0, rv1;
#pragma unroll
        for (int q = 0; q < 4; ++q) {
            rv0[q] = (float)acc0[nt][q] * sxsw;
            rv1[q] = (float)acc1[nt][q] * sxsw;
        }
        float* po = out + ((size_t)(b * OC + o) * HW + oh) * HW;
        *(float4v*)(po + owp) = rv0;
        *(float4v*)(po + owp + 16) = rv1;
    }
}

// ---------------------------------------------------------------------------
extern "C" void kernel_launch(void* const* d_in, const int* in_sizes, int n_in,
                              void* d_out, int out_size, void* d_ws, size_t ws_size,
                              hipStream_t stream) {
    const float* in = (const float*)d_in[0];   // (16, 64, 128, 128) fp32
    const float* wt = (const float*)d_in[1];   // (128, 64, 3, 3) fp32
    float* out = (float*)d_out;                // (16, 128, 128, 128) fp32
    float* wsf = (float*)d_ws;
    char* wq_s = (char*)d_ws + WS_WQ_BYTE_OFF;

    k_absmax<<<dim3(1024 + 144), dim3(256), 0, stream>>>(in, wt, wsf);
    k_scale_wq<<<dim3(128), dim3(576), 0, stream>>>(wt, wsf, wq_s);
    k_gemm<<<dim3(BATCH * HW / 2), dim3(512), 0, stream>>>(in, wq_s, wsf, out);
}

// Round 6
// 260.179 us; speedup vs baseline: 1.6827x; 1.0689x over previous
//
#include <hip/hip_runtime.h>

#define BATCH 16
#define CIN   64
#define HW    128
#define OC    128
#define KSIZE 576   // 64 * 9

typedef float float4v __attribute__((ext_vector_type(4)));
typedef int   int4v   __attribute__((ext_vector_type(4)));
typedef unsigned int uint;

// workspace layout (float offsets)
#define WS_ACT   0      // act_scale[576], k = c*9 + r order
#define WS_WSC   576    // weight_scale[576]
#define WS_XMUL  1152   // xmul[r*64+c] = 1/(scale[c*9+r]*s_x)
#define WS_SXSW  1728
#define WS_WQ_BYTE_OFF 8192   // int8 wq_s[9][128][64], frags XOR-pre-swizzled

#define SWZ(x) ((((x) & 3) ^ (((x) >> 2) & 3)))
#define MAGIC 12582912.0f   // 1.5 * 2^23: fma bias => round-half-even int8 in low byte

__device__ __forceinline__ void async_cp16(const void* g, void* l) {
    __builtin_amdgcn_global_load_lds(
        (const __attribute__((address_space(1))) unsigned int*)g,
        (__attribute__((address_space(3))) unsigned int*)l, 16, 0, 0);
}

// ---------------------------------------------------------------------------
// Kernel 1: fused absmax (unchanged — validated R2-R4).
// ---------------------------------------------------------------------------
__global__ __launch_bounds__(256) void k_absmax(const float* __restrict__ in,
                                                const float* __restrict__ w,
                                                float* __restrict__ wsf) {
    const int tid = threadIdx.x, lane = tid & 63, wid = tid >> 6;
    if (blockIdx.x < 1024) {
        const int c = blockIdx.x >> 4, bs = blockIdx.x & 15;
        const float4v* p = (const float4v*)(in + (size_t)(bs * CIN + c) * (HW * HW));
        float m[9];
#pragma unroll
        for (int i = 0; i < 9; ++i) m[i] = 0.f;
        for (int e = tid; e < 4096; e += 256) {
            const int h = e >> 5, q = e & 31;
            const float4v v = p[e];
            const float a0 = fabsf(v[0]), a1 = fabsf(v[1]), a2 = fabsf(v[2]), a3 = fabsf(v[3]);
            const float m01 = fmaxf(a0, a1), m12 = fmaxf(a1, a2);
            const float mall = fmaxf(m01, fmaxf(a2, a3));
            const float mw0 = (q == 31) ? fmaxf(m01, a2) : mall;
            const float mw2 = (q == 0)  ? fmaxf(m12, a3) : mall;
            const bool h0 = (h <= 126), h2 = (h >= 1);
            m[0] = fmaxf(m[0], h0 ? mw0 : 0.f);
            m[1] = fmaxf(m[1], h0 ? mall : 0.f);
            m[2] = fmaxf(m[2], h0 ? mw2 : 0.f);
            m[3] = fmaxf(m[3], mw0);
            m[4] = fmaxf(m[4], mall);
            m[5] = fmaxf(m[5], mw2);
            m[6] = fmaxf(m[6], h2 ? mw0 : 0.f);
            m[7] = fmaxf(m[7], h2 ? mall : 0.f);
            m[8] = fmaxf(m[8], h2 ? mw2 : 0.f);
        }
#pragma unroll
        for (int i = 0; i < 9; ++i)
            for (int off = 32; off; off >>= 1)
                m[i] = fmaxf(m[i], __shfl_down(m[i], off));
        __shared__ float sred[4][9];
        if (lane == 0)
#pragma unroll
            for (int i = 0; i < 9; ++i) sred[wid][i] = m[i];
        __syncthreads();
        if (tid < 9) {
            float mm = fmaxf(fmaxf(sred[0][tid], sred[1][tid]),
                             fmaxf(sred[2][tid], sred[3][tid]));
            atomicMax((int*)(wsf + WS_ACT + c * 9 + tid), __float_as_int(mm));
        }
    } else {
        const int k = (blockIdx.x - 1024) * 4 + wid;
        float m = fmaxf(fabsf(w[lane * KSIZE + k]), fabsf(w[(lane + 64) * KSIZE + k]));
        for (int off = 32; off; off >>= 1) m = fmaxf(m, __shfl_down(m, off));
        if (lane == 0) wsf[WS_WSC + k] = m;
    }
}

// ---------------------------------------------------------------------------
// Kernel 2: scale + weight quantize -> int8, pre-swizzled (unchanged — validated R3/R4).
// ---------------------------------------------------------------------------
__global__ __launch_bounds__(576) void k_scale_wq(const float* __restrict__ w,
                                                  float* __restrict__ wsf,
                                                  char* __restrict__ wq_s) {
    __shared__ float ls[576];
    __shared__ float redA[9], redB[9];
    const int t = threadIdx.x, o = blockIdx.x;
    const int lane = t & 63, wid = t >> 6;
    const float a = wsf[WS_ACT + t];
    const float wv = wsf[WS_WSC + t];
    float s = sqrtf(a) / sqrtf(wv);
    if (s == 0.f) s = 1.f;
    ls[t] = s;
    float v1 = a / s;
    float v2 = wv * s;
    for (int off = 32; off; off >>= 1) {
        v1 = fmaxf(v1, __shfl_down(v1, off));
        v2 = fmaxf(v2, __shfl_down(v2, off));
    }
    if (lane == 0) { redA[wid] = v1; redB[wid] = v2; }
    __syncthreads();
    float ax = redA[0], aw = redB[0];
#pragma unroll
    for (int i = 1; i < 9; ++i) { ax = fmaxf(ax, redA[i]); aw = fmaxf(aw, redB[i]); }
    const float sx = ax > 0.f ? ax / 127.f : 1.f;
    const float sw = aw > 0.f ? aw / 127.f : 1.f;
    const int r = t >> 6, c = t & 63, ko = c * 9 + r;
    float q = rintf((w[o * KSIZE + ko] * ls[ko]) / sw);
    q = fminf(127.f, fmaxf(-127.f, q));
    const int qi = (int)q;
    const int fc = c >> 4;
    wq_s[r * 8192 + o * 64 + ((fc ^ SWZ(o)) << 4) + (c & 15)] = (char)qi;
    if (o == 0) {
        wsf[WS_XMUL + t] = 1.0f / (ls[ko] * sx);   // [r][c] layout
        if (t == 0) wsf[WS_SXSW] = sx * sw;
    }
}

// ---------------------------------------------------------------------------
// Kernel 3: i8 implicit-GEMM conv, v7: aligned-load A-path (v6b, proven
// correct) + HALVED acc tile to kill the spills (v6b's failure).
// Block = (b, oh): 2048 blocks, 512 thr = 8 waves = 2 oc-halves x 4
// ow-quarters; wave tile 32ow x 64oc -> acc = 8 int4v = 32 AGPR, freeing 96
// arch VGPRs for R0/R1 (32) + shuffle/quantize transients. Per kh-row: 32
// aligned coalesced dwords + 2 edge loads; kw=0/2 fragments via segmented
// shuffles (validated in R4). VMEM 288 (2/3 misaligned) -> 102 aligned
// instr/wave; B ds_reads 4/chunk (1:2 with MFMA). A loads duplicated across
// the 2 oc-half waves (L1-hot) — accepted.
// ---------------------------------------------------------------------------
__global__ __launch_bounds__(512, 4) void k_gemm(const float* __restrict__ in,
                                                 const char* __restrict__ wq_s,
                                                 const float* __restrict__ wsf,
                                                 float* __restrict__ out) {
    __shared__ int4v Bl4[4608];        // 73728 B: 9 planes of [o=128][c=64] i8
    __shared__ float xml[576];
    char* Bl = (char*)Bl4;

    const int tid = threadIdx.x, lane = tid & 63, w = tid >> 6;
    // XCD swizzle: each XCD owns a 16-row oh band per batch (L2 input reuse).
    const int xcd = blockIdx.x & 7, idx = blockIdx.x >> 3;
    const int oh = xcd * 16 + (idx & 15);
    const int b = idx >> 4;
    const int wc = w >> 2, wo = w & 3;     // oc-half, ow-quarter
    const int l15 = lane & 15, fsel = lane >> 4;
    const int W = wo * 32;                 // wave tile ow base
    const int O = wc * 64;                 // wave tile oc base

    // ---- prologue staging (only barrier in the kernel) ----
#pragma unroll
    for (int i = 0; i < 9; ++i)
        async_cp16(wq_s + i * 8192 + tid * 16, Bl + i * 8192 + tid * 16);
    if (tid < 144)
        ((float4v*)xml)[tid] = ((const float4v*)(wsf + WS_XMUL))[tid];
    __syncthreads();

    const float* pb = in + ((size_t)b * CIN + fsel * 16) * (HW * HW);  // row loads
    const float* pe = in + (size_t)b * CIN * (HW * HW);                // edge loads (ch = lane)

    const int colL = (W - 1) < 0 ? 0 : (W - 1);      // clamped; masked if wo==0
    const int colR = (W + 32) > 127 ? 127 : (W + 32);
    const bool isL0  = (l15 == 0);
    const bool isL15 = (l15 == 15);
    const uint mL = (wo == 0 && isL0)  ? 0u : 0xFFFFFFFFu;  // kw0/frag0 OOB lane
    const uint mR = (wo == 3 && isL15) ? 0u : 0xFFFFFFFFu;  // kw2/frag1 OOB lane

    int4v acc0[4], acc1[4];
#pragma unroll
    for (int nt = 0; nt < 4; ++nt) {
        acc0[nt] = (int4v){0, 0, 0, 0};
        acc1[nt] = (int4v){0, 0, 0, 0};
    }

#pragma unroll
    for (int kh = 0; kh < 3; ++kh) {
        const int h = oh + kh - 1;
        if (h >= 0 && h < HW) {            // wave-uniform skip
            // ---- edge columns first (scattered; L1-hot across waves) ----
            const float eL = pe[(size_t)lane * (HW * HW) + h * HW + colL];
            const float eR = pe[(size_t)lane * (HW * HW) + h * HW + colR];
            // ---- aligned row loads: 32 coalesced dwords ----
            const float* p = pb + h * HW + W + l15;
            float R0[16], R1[16];
#pragma unroll
            for (int j = 0; j < 16; ++j) {
                R0[j] = p[j * (HW * HW)];
                R1[j] = p[j * (HW * HW) + 16];
            }
            // ---- per-kw: build fragments via shifts, quantize, MFMA ----
#pragma unroll
            for (int kw = 0; kw < 3; ++kw) {
                const int r = kh * 3 + kw;
                const float* xp = xml + r * 64 + (fsel << 4);
                uint pk0[4], pk1[4];
#pragma unroll
                for (int d = 0; d < 4; ++d) {
                    const float4v xq = *(const float4v*)(xp + d * 4);
                    uint u0[4], u1[4];
#pragma unroll
                    for (int j2 = 0; j2 < 4; ++j2) {
                        const int j = d * 4 + j2;
                        float a0, a1;
                        if (kw == 1) {
                            a0 = R0[j];
                            a1 = R1[j];
                        } else if (kw == 0) {
                            const float t0 = __shfl_up(R0[j], 1, 16);
                            const float ev = __shfl(eL, j, 16);      // seg-bcast: seg lane j holds ch fsel*16+j
                            a0 = isL0 ? ev : t0;
                            const float t1 = __shfl_up(R1[j], 1, 16);
                            const float bb = __shfl(R0[j], 15, 16);  // seg lane 15 bcast
                            a1 = isL0 ? bb : t1;
                        } else {   // kw == 2
                            const float t0 = __shfl_down(R0[j], 1, 16);
                            const float bb = __shfl(R1[j], 0, 16);   // seg lane 0 bcast
                            a0 = isL15 ? bb : t0;
                            const float t1 = __shfl_down(R1[j], 1, 16);
                            const float ev = __shfl(eR, j, 16);      // seg-bcast (R4 fix)
                            a1 = isL15 ? ev : t1;
                        }
                        u0[j2] = __float_as_uint(fmaf(a0, xq[j2], MAGIC));
                        u1[j2] = __float_as_uint(fmaf(a1, xq[j2], MAGIC));
                    }
                    const uint a01 = __builtin_amdgcn_perm(u0[1], u0[0], 0x0C0C0400u);
                    const uint a23 = __builtin_amdgcn_perm(u0[3], u0[2], 0x0C0C0400u);
                    pk0[d] = __builtin_amdgcn_perm(a23, a01, 0x05040100u);
                    const uint b01 = __builtin_amdgcn_perm(u1[1], u1[0], 0x0C0C0400u);
                    const uint b23 = __builtin_amdgcn_perm(u1[3], u1[2], 0x0C0C0400u);
                    pk1[d] = __builtin_amdgcn_perm(b23, b01, 0x05040100u);
                }
                int4v af0, af1;
                if (kw == 0) {             // frag0 lane0 may be image-left OOB
                    af0 = (int4v){(int)(pk0[0] & mL), (int)(pk0[1] & mL),
                                  (int)(pk0[2] & mL), (int)(pk0[3] & mL)};
                    af1 = (int4v){(int)pk1[0], (int)pk1[1], (int)pk1[2], (int)pk1[3]};
                } else if (kw == 2) {      // frag1 lane15 may be image-right OOB
                    af0 = (int4v){(int)pk0[0], (int)pk0[1], (int)pk0[2], (int)pk0[3]};
                    af1 = (int4v){(int)(pk1[0] & mR), (int)(pk1[1] & mR),
                                  (int)(pk1[2] & mR), (int)(pk1[3] & mR)};
                } else {
                    af0 = (int4v){(int)pk0[0], (int)pk0[1], (int)pk0[2], (int)pk0[3]};
                    af1 = (int4v){(int)pk1[0], (int)pk1[1], (int)pk1[2], (int)pk1[3]};
                }
                // ---- B frags: this wave's oc-half only (4 reads, 8 MFMA) ----
#pragma unroll
                for (int nt = 0; nt < 4; ++nt) {
                    const int br = O + nt * 16 + l15;
                    const int4v bf = *(const int4v*)(Bl + r * 8192 + br * 64 +
                                                     ((fsel ^ SWZ(br)) << 4));
                    acc0[nt] = __builtin_amdgcn_mfma_i32_16x16x64_i8(af0, bf, acc0[nt], 0, 0, 0);
                    acc1[nt] = __builtin_amdgcn_mfma_i32_16x16x64_i8(af1, bf, acc1[nt], 0, 0, 0);
                }
            }
        }
    }

    // ---- epilogue: row=(lane>>4)*4+reg -> ow, col=lane&15 -> o ----
    const float sxsw = wsf[WS_SXSW];
    const int owp = W + (fsel << 2);
#pragma unroll
    for (int nt = 0; nt < 4; ++nt) {
        const int o = O + nt * 16 + l15;
        float4v rv0, rv1;
#pragma unroll
        for (int q = 0; q < 4; ++q) {
            rv0[q] = (float)acc0[nt][q] * sxsw;
            rv1[q] = (float)acc1[nt][q] * sxsw;
        }
        float* po = out + ((size_t)(b * OC + o) * HW + oh) * HW;
        *(float4v*)(po + owp) = rv0;
        *(float4v*)(po + owp + 16) = rv1;
    }
}

// ---------------------------------------------------------------------------
extern "C" void kernel_launch(void* const* d_in, const int* in_sizes, int n_in,
                              void* d_out, int out_size, void* d_ws, size_t ws_size,
                              hipStream_t stream) {
    const float* in = (const float*)d_in[0];   // (16, 64, 128, 128) fp32
    const float* wt = (const float*)d_in[1];   // (128, 64, 3, 3) fp32
    float* out = (float*)d_out;                // (16, 128, 128, 128) fp32
    float* wsf = (float*)d_ws;
    char* wq_s = (char*)d_ws + WS_WQ_BYTE_OFF;

    k_absmax<<<dim3(1024 + 144), dim3(256), 0, stream>>>(in, wt, wsf);
    k_scale_wq<<<dim3(128), dim3(576), 0, stream>>>(wt, wsf, wq_s);
    k_gemm<<<dim3(BATCH * HW), dim3(512), 0, stream>>>(in, wq_s, wsf, out);
}